// Round 11
// baseline (1774.899 us; speedup 1.0000x reference)
//
#include <hip/hip_runtime.h>
#include <math.h>

#define BB 16
#define DTOT 544
#define TT_DIM 4096
#define DS 512
#define NCODES 4096
#define HALFV 7.5f
#define EPSV 1e-5f
#define NROWS (BB * TT_DIM)          // 65536
#define NT 16                        // 4096 / 256
#define MT 256                       // 65536 / 256
#define REFINE_THR 0.05f
#define TT 32                        // t per block in k_sem

typedef short bf16x8 __attribute__((ext_vector_type(8)));
typedef float f32x4 __attribute__((ext_vector_type(4)));
typedef float f32x16 __attribute__((ext_vector_type(16)));

__device__ __forceinline__ unsigned short f2bf(float v) {
    unsigned u = __float_as_uint(v);
    unsigned r = (u + 0x7fffu + ((u >> 16) & 1u)) >> 16;
    return (unsigned short)r;
}
__device__ __forceinline__ float bf2f(unsigned short h) {
    return __uint_as_float((unsigned)h << 16);
}

// ---------------- kernel: emb fp32 + e2 + zero flag counter ----------------
__global__ __launch_bounds__(256) void k_emb(const float* __restrict__ esum,
                                             const float* __restrict__ usage,
                                             float* __restrict__ emb,
                                             float* __restrict__ e2,
                                             int* __restrict__ counter) {
    int c = blockIdx.x;
    if (c == 0 && threadIdx.x == 0) *counter = 0;
    float u = usage[c];
    u = (u < EPSV) ? EPSV : u;
    float s = 0.f;
#pragma unroll
    for (int i = 0; i < 2; i++) {
        int d = threadIdx.x + i * 256;
        float v = esum[(size_t)c * DS + d] / u;
        emb[(size_t)c * DS + d] = v;
        s += v * v;
    }
#pragma unroll
    for (int o = 32; o; o >>= 1) s += __shfl_down(s, o, 64);
    __shared__ float red[4];
    if ((threadIdx.x & 63) == 0) red[threadIdx.x >> 6] = s;
    __syncthreads();
    if (threadIdx.x == 0) e2[c] = red[0] + red[1] + red[2] + red[3];
}

// ---------------- pack A: x sem -> 256row x 32K bf16 tiles (chunks: 16 hi, 16 lo) ----------------
// tile byte layout (matches LDS image): off = row*64 + ((u ^ ((row>>1)&3))<<4) + (k&7)*2, u = k>>3
__global__ __launch_bounds__(256) void k_packA(const float* __restrict__ x,
                                               char* __restrict__ Ap) {
    __shared__ char ldsH[16384];
    __shared__ char ldsL[16384];
    int mt = blockIdx.x, dc = blockIdx.y;
    int b = mt >> 4;
    int t0 = (mt & 15) * 256;
    int tid = threadIdx.x;
#pragma unroll
    for (int i = 0; i < 8; i++) {
        int idx = tid + i * 256;
        int d = idx >> 6;            // 0..31
        int t4 = idx & 63;           // 0..63
        float4 v = *(const float4*)&x[((size_t)b * DTOT + dc * 32 + d) * TT_DIM + t0 + t4 * 4];
        float va[4] = {v.x, v.y, v.z, v.w};
        int u = d >> 3;
        int kb = (d & 7) * 2;
#pragma unroll
        for (int j = 0; j < 4; j++) {
            int row = t4 * 4 + j;
            unsigned short hi = f2bf(va[j]);
            unsigned short lo = f2bf(va[j] - bf2f(hi));
            int off = row * 64 + ((u ^ ((row >> 1) & 3)) << 4) + kb;
            *(unsigned short*)&ldsH[off] = hi;
            *(unsigned short*)&ldsL[off] = lo;
        }
    }
    __syncthreads();
    char* gH = Ap + ((size_t)mt * 32 + dc) * 16384;
    char* gL = Ap + ((size_t)mt * 32 + 16 + dc) * 16384;
#pragma unroll
    for (int i = 0; i < 4; i++) {
        int off = (tid + i * 256) * 16;
        *(uint4*)&gH[off] = *(const uint4*)&ldsH[off];
        *(uint4*)&gL[off] = *(const uint4*)&ldsL[off];
    }
}

// ---------------- pack B: emb -> 256code x 32K bf16 tiles (chunks: 16 hi, 16 lo) ----------------
__global__ __launch_bounds__(256) void k_packB(const float* __restrict__ emb,
                                               char* __restrict__ Bp) {
    __shared__ char ldsT[16384];
    int nt = blockIdx.x, c = blockIdx.y;
    int lo_flag = (c >= 16);
    int d0 = (lo_flag ? (c - 16) : c) * 32;
    int c0 = nt * 256;
    int tid = threadIdx.x;
#pragma unroll
    for (int i = 0; i < 8; i++) {
        int idx = tid + i * 256;
        int row = idx >> 3;          // code 0..255
        int f4 = idx & 7;            // d-float4 0..7
        float4 v = *(const float4*)&emb[(size_t)(c0 + row) * DS + d0 + f4 * 4];
        float va[4] = {v.x, v.y, v.z, v.w};
        unsigned short wv[4];
#pragma unroll
        for (int j = 0; j < 4; j++) {
            unsigned short hi = f2bf(va[j]);
            wv[j] = lo_flag ? f2bf(va[j] - bf2f(hi)) : hi;
        }
        int u = f4 >> 1;
        int off = row * 64 + ((u ^ ((row >> 1) & 3)) << 4) + (f4 & 1) * 8;
        uint2 pk;
        pk.x = ((unsigned)wv[1] << 16) | wv[0];
        pk.y = ((unsigned)wv[3] << 16) | wv[2];
        *(uint2*)&ldsT[off] = pk;
    }
    __syncthreads();
    char* g = Bp + ((size_t)nt * 32 + c) * 16384;
#pragma unroll
    for (int i = 0; i < 4; i++) {
        int off = (tid + i * 256) * 16;
        *(uint4*)&g[off] = *(const uint4*)&ldsT[off];
    }
}

// ---------------- MFMA distance-argmin: 256x256 tile, 32x32x16 MFMA, reg-prefetch pipeline ----------------
// Sync skeleton identical to round 10 (passed): 4-slot ring, slot s staged at chunk s-3,
// prefetch-read (B-all + A-kstep0) at chunk s-1, A-kstep1 re-read at chunk s, vmcnt(4)+barrier
// per chunk. Only the MFMA shape changed: 16 x mfma_f32_32x32x16_bf16 per chunk per wave
// (was 32 x 16x16x32). A/B lane map: row = l&31, k = (l>>5)*8 + j. C/D: col = l&31,
// row = (r&3) + 8*(r>>2) + 4*(l>>5)  [m74/m101 verified].
#define MM32(A, B, C) __builtin_amdgcn_mfma_f32_32x32x16_bf16((A), (B), (C), 0, 0, 0)

#define GLDS(SRC, DOFF)                                                              \
    __builtin_amdgcn_global_load_lds(                                                \
        (const __attribute__((address_space(1))) void*)(SRC),                        \
        (__attribute__((address_space(3))) void*)&lds[DOFF], 16, 0, 0)

#define BAR __builtin_amdgcn_s_barrier()
#define VMW4 asm volatile("s_waitcnt vmcnt(4)" ::: "memory")
#define VMW0 asm volatile("s_waitcnt vmcnt(0)" ::: "memory")
#define VMNONE (void)0

#define STAGE_A(C, S) do {                                                           \
    int c_ = (C);                                                                    \
    int at_ = (c_ < 32) ? (c_ & 15) : (c_ - 16);                                     \
    const char* sp_ = Ap_mt + at_ * 16384;                                           \
    GLDS(sp_ + t16,        (S) * 16384 + t16);                                       \
    GLDS(sp_ + t16 + 8192, (S) * 16384 + t16 + 8192);                                \
} while (0)

#define STAGE_B(C, S) do {                                                           \
    int c_ = (C);                                                                    \
    int bt_ = (c_ < 32) ? c_ : (c_ - 32);                                            \
    const char* sp_ = Bp_nt + bt_ * 16384;                                           \
    GLDS(sp_ + t16,        65536 + (S) * 16384 + t16);                               \
    GLDS(sp_ + t16 + 8192, 65536 + (S) * 16384 + t16 + 8192);                        \
} while (0)

// prefetch all 4 B-frags + A-kstep0 frags of slot PS into (BUFB, BUFA)
#define RD8(BUFB, BUFA, PS) do {                                                     \
    BUFB[0] = *(const bf16x8*)&lds[offB00 + (PS) * 16384];                           \
    BUFB[1] = *(const bf16x8*)&lds[offB01 + (PS) * 16384];                           \
    BUFB[2] = *(const bf16x8*)&lds[offB10 + (PS) * 16384];                           \
    BUFB[3] = *(const bf16x8*)&lds[offB11 + (PS) * 16384];                           \
    BUFA[0] = *(const bf16x8*)&lds[offA0 + (PS) * 16384];                            \
    BUFA[1] = *(const bf16x8*)&lds[offA0 + (PS) * 16384 + 2048];                     \
    BUFA[2] = *(const bf16x8*)&lds[offA0 + (PS) * 16384 + 4096];                     \
    BUFA[3] = *(const bf16x8*)&lds[offA0 + (PS) * 16384 + 6144];                     \
} while (0)

// read A-kstep1 frags of slot S into BUFA (reuses consumed kstep0 registers)
#define RDH1(BUFA, S) do {                                                           \
    BUFA[0] = *(const bf16x8*)&lds[offA1 + (S) * 16384];                             \
    BUFA[1] = *(const bf16x8*)&lds[offA1 + (S) * 16384 + 2048];                      \
    BUFA[2] = *(const bf16x8*)&lds[offA1 + (S) * 16384 + 4096];                      \
    BUFA[3] = *(const bf16x8*)&lds[offA1 + (S) * 16384 + 6144];                      \
} while (0)

// 8 MFMA (4 m-tiles x 2 n-tiles) for kstep H
#define MF8(H, BUFB, BUFA) do {                                                      \
    __builtin_amdgcn_s_setprio(1);                                                   \
    _Pragma("unroll")                                                                \
    for (int m_ = 0; m_ < 4; m_++)                                                   \
        _Pragma("unroll")                                                            \
        for (int n_ = 0; n_ < 2; n_++)                                               \
            acc[m_ * 2 + n_] = MM32(BUFA[m_], BUFB[n_ * 2 + (H)], acc[m_ * 2 + n_]); \
    __builtin_amdgcn_s_setprio(0);                                                   \
} while (0)

// one chunk: prefetch next-slot frags + stage chunk s+3, then 2x8 MFMA on current frags
#define CHUNK(S, CURB, CURA, NXTB, NXTA, DO_PREF, DO_STG, STG_C, VMEND, DO_BAR) do { \
    if (DO_PREF) RD8(NXTB, NXTA, ((S) + 1) & 3);                                     \
    if (DO_STG) { STAGE_A((STG_C), ((S) + 3) & 3); STAGE_B((STG_C), ((S) + 3) & 3); }\
    __builtin_amdgcn_sched_barrier(0);                                               \
    MF8(0, CURB, CURA);                                                              \
    RDH1(CURA, (S));                                                                 \
    MF8(1, CURB, CURA);                                                              \
    VMEND;                                                                           \
    if (DO_BAR) BAR;                                                                 \
} while (0)

__global__ __launch_bounds__(512) void k_mfma(const char* __restrict__ Ap,
                                              const char* __restrict__ Bp,
                                              const float* __restrict__ e2,
                                              float* __restrict__ pb,
                                              int* __restrict__ pi,
                                              float* __restrict__ ps) {
    extern __shared__ char lds[];
    // XCD-bijective swizzle: 4096 blocks, 8 XCDs -> 512 consecutive lin per XCD
    int bid = blockIdx.x;
    int lin = (bid >> 3) + (bid & 7) * 512;
    int nt = lin & 15;
    int mt = lin >> 4;

    int tid = threadIdx.x;
    int lane = tid & 63;
    int w = tid >> 6;
    int wr = w >> 2, wc = w & 3;
    int l31 = lane & 31, lk = lane >> 5;
    int t16 = tid * 16;

    const char* Ap_mt = Ap + (size_t)mt * 32 * 16384;
    const char* Bp_nt = Bp + (size_t)nt * 32 * 16384;

    // 32x32x16 fragment byte offsets. Per lane: row = base + l31, u = 2*kstep + lk,
    // off = row*64 + ((u ^ ((row>>1)&3))<<4). swizzle bits depend only on l31.
    int sw = (l31 >> 1) & 3;
    int offA0 = (wr * 128 + l31) * 64 + (((0 * 2 + lk) ^ sw) << 4);          // kstep0, mt-tile stride 2048
    int offA1 = (wr * 128 + l31) * 64 + (((1 * 2 + lk) ^ sw) << 4);          // kstep1
    int offB00 = 65536 + (wc * 64 + l31) * 64 + ((lk ^ sw) << 4);            // nt0, kstep0
    int offB01 = 65536 + (wc * 64 + l31) * 64 + (((2 + lk) ^ sw) << 4);      // nt0, kstep1
    int offB10 = 65536 + (wc * 64 + 32 + l31) * 64 + ((lk ^ sw) << 4);       // nt1, kstep0
    int offB11 = 65536 + (wc * 64 + 32 + l31) * 64 + (((2 + lk) ^ sw) << 4); // nt1, kstep1

    f32x16 acc[8];
#pragma unroll
    for (int m = 0; m < 8; m++)
#pragma unroll
        for (int r = 0; r < 16; r++) acc[m][r] = 0.f;

    bf16x8 bX[4], aX[4], bY[4], aY[4];

    // prologue: stage chunks 0,1,2 -> slots 0,1,2; drain slots 0,1; initial frags
    STAGE_A(0, 0); STAGE_B(0, 0);
    STAGE_A(1, 1); STAGE_B(1, 1);
    STAGE_A(2, 2); STAGE_B(2, 2);
    VMW4;                      // own slots 0,1 drained
    BAR;                       // all waves' slots 0,1 in LDS
    RD8(bX, aX, 0);            // chunk 0 frags (B-all + A-kstep0)

#pragma unroll 1
    for (int j = 0; j < 11; j++) {
        int c = 4 * j;
        CHUNK(0, bX, aX, bY, aY, 1, 1, c + 3, VMW4, 1);
        CHUNK(1, bY, aY, bX, aX, 1, 1, c + 4, VMW4, 1);
        CHUNK(2, bX, aX, bY, aY, 1, 1, c + 5, VMW4, 1);
        CHUNK(3, bY, aY, bX, aX, 1, 1, c + 6, VMW4, 1);
    }
    // peeled chunks 44..47
    CHUNK(0, bX, aX, bY, aY, 1, 1, 47, VMW4, 1);    // 44: stage chunk 47 -> slot 3
    CHUNK(1, bY, aY, bX, aX, 1, 0, 0, VMW0, 1);     // 45: drain chunk 47
    CHUNK(2, bX, aX, bY, aY, 1, 0, 0, VMNONE, 1);   // 46: prefetch slot 3 (chunk 47)
    CHUNK(3, bY, aY, bX, aX, 0, 0, 0, VMNONE, 0);   // 47: compute only

    // ---------------- epilogue: per-row argmin (32x32 C/D layout) ----------------
    __syncthreads();
    float* rb = (float*)lds;
    float* rs = (float*)(lds + 4096);
    int*   ri = (int*)(lds + 8192);

    float e2v0 = e2[nt * 256 + wc * 64 + l31];
    float e2v1 = e2[nt * 256 + wc * 64 + 32 + l31];
    int i0 = wc * 64 + l31;
    int i1 = wc * 64 + 32 + l31;

#pragma unroll
    for (int mtl = 0; mtl < 4; mtl++) {
#pragma unroll
        for (int r = 0; r < 16; r++) {
            float v0 = e2v0 - 2.f * acc[mtl * 2][r];
            float v1 = e2v1 - 2.f * acc[mtl * 2 + 1][r];
            float bst, sec; int bi;
            if (v0 < v1 || (v0 == v1 && i0 < i1)) { bst = v0; bi = i0; sec = v1; }
            else { bst = v1; bi = i1; sec = v0; }
#pragma unroll
            for (int mask = 1; mask <= 16; mask <<= 1) {
                float ob = __shfl_xor(bst, mask);
                int obi = __shfl_xor(bi, mask);
                float os = __shfl_xor(sec, mask);
                if (ob < bst || (ob == bst && obi < bi)) {
                    sec = fminf(bst, os); bst = ob; bi = obi;
                } else {
                    sec = fminf(sec, ob);
                }
            }
            if (l31 == 0) {
                int rl = wr * 128 + mtl * 32 + (r & 3) + 8 * (r >> 2) + 4 * lk;
                int slot = wc * 256 + rl;
                rb[slot] = bst; rs[slot] = sec; ri[slot] = nt * 256 + bi;
            }
        }
    }
    __syncthreads();
    if (tid < 256) {
        float bsv = rb[tid], ssv = rs[tid];
        int biv = ri[tid];
#pragma unroll
        for (int c = 1; c < 4; c++) {
            float ob = rb[c * 256 + tid];
            float os = rs[c * 256 + tid];
            int oi = ri[c * 256 + tid];
            if (ob < bsv || (ob == bsv && oi < biv)) { ssv = fminf(bsv, os); bsv = ob; biv = oi; }
            else ssv = fminf(ssv, ob);
        }
        size_t gr = (size_t)mt * 256 + tid;
        pb[(size_t)nt * NROWS + gr] = bsv;
        pi[(size_t)nt * NROWS + gr] = biv;
        ps[(size_t)nt * NROWS + gr] = ssv;
    }
}

// ---------------- reduce partials -> codes + flagged rows ----------------
__global__ __launch_bounds__(256) void k_reduce(const float* __restrict__ pb,
                                                const int* __restrict__ pi,
                                                const float* __restrict__ ps,
                                                int* __restrict__ codes,
                                                int* __restrict__ list,
                                                int* __restrict__ counter) {
    int row = blockIdx.x * 256 + threadIdx.x;
    float b = 3.4e38f, s = 3.4e38f;
    int bi = 1 << 30;
    for (int nt = 0; nt < NT; nt++) {
        float b2 = pb[(size_t)nt * NROWS + row];
        int i2 = pi[(size_t)nt * NROWS + row];
        float s2 = ps[(size_t)nt * NROWS + row];
        if (b2 < b || (b2 == b && i2 < bi)) { s = fminf(b, s2); b = b2; bi = i2; }
        else s = fminf(s, b2);
    }
    codes[row] = bi;
    if (s - b < REFINE_THR) {
        int p = atomicAdd(counter, 1);
        list[p] = row;
    }
}

// ---------------- fp64 full-scan refine of flagged rows ----------------
__global__ __launch_bounds__(256) void k_refine(const float* __restrict__ x,
                                                const float* __restrict__ emb,
                                                int* __restrict__ codes,
                                                const int* __restrict__ list,
                                                const int* __restrict__ counter) {
    __shared__ float xrow[DS];
    __shared__ double redv[256];
    __shared__ int redi[256];
    int tid = threadIdx.x;
    int nflag = *counter;
    for (int it = blockIdx.x; it < nflag; it += gridDim.x) {
        int row = list[it];
        int b = row >> 12;
        int t = row & 4095;
        for (int d = tid; d < DS; d += 256)
            xrow[d] = x[((size_t)b * DTOT + d) * TT_DIM + t];
        __syncthreads();
        double bv = 1e300;
        int bi = 1 << 30;
        for (int c = tid; c < NCODES; c += 256) {
            const float* er = emb + (size_t)c * DS;
            double s = 0.0;
            for (int d = 0; d < DS; d += 4) {
                float4 ev = *(const float4*)&er[d];
                float4 xv = *(const float4*)&xrow[d];
                double d0 = (double)xv.x - (double)ev.x;
                double d1 = (double)xv.y - (double)ev.y;
                double d2 = (double)xv.z - (double)ev.z;
                double d3 = (double)xv.w - (double)ev.w;
                s += d0 * d0 + d1 * d1 + d2 * d2 + d3 * d3;
            }
            if (s < bv || (s == bv && c < bi)) { bv = s; bi = c; }
        }
        redv[tid] = bv; redi[tid] = bi;
        __syncthreads();
        for (int off = 128; off; off >>= 1) {
            if (tid < off) {
                if (redv[tid + off] < redv[tid] ||
                    (redv[tid + off] == redv[tid] && redi[tid + off] < redi[tid])) {
                    redv[tid] = redv[tid + off];
                    redi[tid] = redi[tid + off];
                }
            }
            __syncthreads();
        }
        if (tid == 0) codes[row] = redi[0];
        __syncthreads();
    }
}

// ---------------- sem output (gather or copy) + sem codes ----------------
__global__ __launch_bounds__(256) void k_sem(const float* __restrict__ x,
                                             const float* __restrict__ emb,
                                             const int* __restrict__ codes,
                                             const float* __restrict__ sem_probs,
                                             float* __restrict__ out) {
    __shared__ float q[TT * (DS + 1)];
    __shared__ int rowc[TT];
    int b = blockIdx.y, t0 = blockIdx.x * TT;
    bool mask = sem_probs[b] < 0.5f;
    float* outb = out + (size_t)b * DTOT * TT_DIM + t0;
    const float* xb = x + (size_t)b * DTOT * TT_DIM + t0;
    const size_t QOFF = (size_t)BB * DTOT * TT_DIM;

    if (threadIdx.x < TT) {
        int code = codes[b * TT_DIM + t0 + threadIdx.x];
        rowc[threadIdx.x] = code;
        out[QOFF + ((size_t)b * 33) * TT_DIM + t0 + threadIdx.x] = (float)code;
    }
    __syncthreads();

    if (mask) {
        for (int i = 0; i < TT * DS / 256; i++) {
            int idx = threadIdx.x + i * 256;
            int tt = idx >> 9, d = idx & 511;
            q[tt * (DS + 1) + d] = emb[(size_t)rowc[tt] * DS + d];
        }
        __syncthreads();
        for (int i = 0; i < TT * DS / 256; i++) {
            int idx = threadIdx.x + i * 256;
            int d = idx >> 5, tt = idx & 31;
            outb[(size_t)d * TT_DIM + tt] = q[tt * (DS + 1) + d];
        }
    } else {
        for (int i = 0; i < TT * DS / 256; i++) {
            int idx = threadIdx.x + i * 256;
            int d = idx >> 5, tt = idx & 31;
            outb[(size_t)d * TT_DIM + tt] = xb[(size_t)d * TT_DIM + tt];
        }
    }
}

// ---------------- aco elementwise ----------------
__global__ __launch_bounds__(256) void k_aco(const float* __restrict__ x,
                                             const float* __restrict__ noise,
                                             const float* __restrict__ aco_probs,
                                             float* __restrict__ out) {
    int idx = blockIdx.x * 256 + threadIdx.x;
    int t4 = idx & 1023;
    int bc = idx >> 10;
    int ch = bc & 31;
    int b = bc >> 5;
    const float4 xv = *(const float4*)&x[((size_t)(b * DTOT + DS + ch)) * TT_DIM + t4 * 4];
    const float4 nv = *(const float4*)&noise[((size_t)(b * 32 + ch)) * TT_DIM + t4 * 4];
    float p = aco_probs[b];
    const size_t QOFF = (size_t)BB * DTOT * TT_DIM;

    float zq[4], cq[4];
    float xa[4] = {xv.x, xv.y, xv.z, xv.w};
    float na[4] = {nv.x, nv.y, nv.z, nv.w};
#pragma unroll
    for (int i = 0; i < 4; i++) {
        float zb = tanhf(xa[i]) * HALFV;
        float z;
        if (p < 0.5f) z = rintf(zb);
        else if (p < 0.75f) z = fminf(fmaxf(zb + na[i], -HALFV), HALFV);
        else z = zb;
        zq[i] = z / HALFV;
        cq[i] = fminf(fmaxf(rintf(z + HALFV), 0.f), 15.f);
    }
    float4 qo = {zq[0], zq[1], zq[2], zq[3]};
    float4 co = {cq[0], cq[1], cq[2], cq[3]};
    *(float4*)&out[((size_t)(b * DTOT + DS + ch)) * TT_DIM + t4 * 4] = qo;
    *(float4*)&out[QOFF + ((size_t)(b * 33 + 1 + ch)) * TT_DIM + t4 * 4] = co;
}

extern "C" void kernel_launch(void* const* d_in, const int* in_sizes, int n_in,
                              void* d_out, int out_size, void* d_ws, size_t ws_size,
                              hipStream_t stream) {
    const float* x         = (const float*)d_in[0];
    const float* esum      = (const float*)d_in[1];
    const float* usage     = (const float*)d_in[2];
    const float* sem_probs = (const float*)d_in[3];
    const float* aco_probs = (const float*)d_in[4];
    const float* noise     = (const float*)d_in[5];
    float* out = (float*)d_out;

    char* w = (char*)d_ws;
    float* emb    = (float*)w;                         // 8,388,608
    float* e2     = (float*)(w + 8388608);             // 16,384
    char*  Ap     = w + 8404992;                       // 134,217,728
    char*  Bp     = w + 142622720;                     // 8,388,608
    float* pb     = (float*)(w + 151011328);           // 4,194,304
    int*   pi     = (int*)(w + 155205632);             // 4,194,304
    float* ps     = (float*)(w + 159399936);           // 4,194,304
    int*   codes  = (int*)(w + 163594240);             // 262,144
    int*   list   = (int*)(w + 163856384);             // 262,144
    int*   counter= (int*)(w + 164118528);             // 4

    k_emb<<<NCODES, 256, 0, stream>>>(esum, usage, emb, e2, counter);
    k_packA<<<dim3(MT, 16), 256, 0, stream>>>(x, Ap);
    k_packB<<<dim3(NT, 32), 256, 0, stream>>>(emb, Bp);
    k_mfma<<<NT * MT, 512, 131072, stream>>>(Ap, Bp, e2, pb, pi, ps);
    k_reduce<<<NROWS / 256, 256, 0, stream>>>(pb, pi, ps, codes, list, counter);
    k_refine<<<256, 256, 0, stream>>>(x, emb, codes, list, counter);
    k_sem<<<dim3(TT_DIM / TT, BB), 256, 0, stream>>>(x, emb, codes, sem_probs, out);
    k_aco<<<(BB * 32 * TT_DIM) / (256 * 4), 256, 0, stream>>>(x, noise, aco_probs, out);
}

// Round 12
// 1185.268 us; speedup vs baseline: 1.4975x; 1.4975x over previous
//
#include <hip/hip_runtime.h>
#include <math.h>

#define BB 16
#define DTOT 544
#define TT_DIM 4096
#define DS 512
#define NCODES 4096
#define HALFV 7.5f
#define EPSV 1e-5f
#define NROWS (BB * TT_DIM)          // 65536
#define NT 16                        // 4096 / 256
#define MT 256                       // 65536 / 256
#define REFINE_THR 0.05f
#define TT 32                        // t per block in k_sem

typedef short bf16x8 __attribute__((ext_vector_type(8)));
typedef float f32x4 __attribute__((ext_vector_type(4)));

__device__ __forceinline__ unsigned short f2bf(float v) {
    unsigned u = __float_as_uint(v);
    unsigned r = (u + 0x7fffu + ((u >> 16) & 1u)) >> 16;
    return (unsigned short)r;
}
__device__ __forceinline__ float bf2f(unsigned short h) {
    return __uint_as_float((unsigned)h << 16);
}

// ---------------- kernel: emb fp32 + e2 + zero flag counter ----------------
__global__ __launch_bounds__(256) void k_emb(const float* __restrict__ esum,
                                             const float* __restrict__ usage,
                                             float* __restrict__ emb,
                                             float* __restrict__ e2,
                                             int* __restrict__ counter) {
    int c = blockIdx.x;
    if (c == 0 && threadIdx.x == 0) *counter = 0;
    float u = usage[c];
    u = (u < EPSV) ? EPSV : u;
    float s = 0.f;
#pragma unroll
    for (int i = 0; i < 2; i++) {
        int d = threadIdx.x + i * 256;
        float v = esum[(size_t)c * DS + d] / u;
        emb[(size_t)c * DS + d] = v;
        s += v * v;
    }
#pragma unroll
    for (int o = 32; o; o >>= 1) s += __shfl_down(s, o, 64);
    __shared__ float red[4];
    if ((threadIdx.x & 63) == 0) red[threadIdx.x >> 6] = s;
    __syncthreads();
    if (threadIdx.x == 0) e2[c] = red[0] + red[1] + red[2] + red[3];
}

// ---------------- pack A: x sem -> 256row x 32K bf16 tiles (chunks: 16 hi, 16 lo) ----------------
// tile byte layout (matches LDS image): off = row*64 + ((u ^ ((row>>1)&3))<<4) + (k&7)*2, u = k>>3
__global__ __launch_bounds__(256) void k_packA(const float* __restrict__ x,
                                               char* __restrict__ Ap) {
    __shared__ char ldsH[16384];
    __shared__ char ldsL[16384];
    int mt = blockIdx.x, dc = blockIdx.y;
    int b = mt >> 4;
    int t0 = (mt & 15) * 256;
    int tid = threadIdx.x;
#pragma unroll
    for (int i = 0; i < 8; i++) {
        int idx = tid + i * 256;
        int d = idx >> 6;            // 0..31
        int t4 = idx & 63;           // 0..63
        float4 v = *(const float4*)&x[((size_t)b * DTOT + dc * 32 + d) * TT_DIM + t0 + t4 * 4];
        float va[4] = {v.x, v.y, v.z, v.w};
        int u = d >> 3;
        int kb = (d & 7) * 2;
#pragma unroll
        for (int j = 0; j < 4; j++) {
            int row = t4 * 4 + j;
            unsigned short hi = f2bf(va[j]);
            unsigned short lo = f2bf(va[j] - bf2f(hi));
            int off = row * 64 + ((u ^ ((row >> 1) & 3)) << 4) + kb;
            *(unsigned short*)&ldsH[off] = hi;
            *(unsigned short*)&ldsL[off] = lo;
        }
    }
    __syncthreads();
    char* gH = Ap + ((size_t)mt * 32 + dc) * 16384;
    char* gL = Ap + ((size_t)mt * 32 + 16 + dc) * 16384;
#pragma unroll
    for (int i = 0; i < 4; i++) {
        int off = (tid + i * 256) * 16;
        *(uint4*)&gH[off] = *(const uint4*)&ldsH[off];
        *(uint4*)&gL[off] = *(const uint4*)&ldsL[off];
    }
}

// ---------------- pack B: emb -> 256code x 32K bf16 tiles (chunks: 16 hi, 16 lo) ----------------
__global__ __launch_bounds__(256) void k_packB(const float* __restrict__ emb,
                                               char* __restrict__ Bp) {
    __shared__ char ldsT[16384];
    int nt = blockIdx.x, c = blockIdx.y;
    int lo_flag = (c >= 16);
    int d0 = (lo_flag ? (c - 16) : c) * 32;
    int c0 = nt * 256;
    int tid = threadIdx.x;
#pragma unroll
    for (int i = 0; i < 8; i++) {
        int idx = tid + i * 256;
        int row = idx >> 3;          // code 0..255
        int f4 = idx & 7;            // d-float4 0..7
        float4 v = *(const float4*)&emb[(size_t)(c0 + row) * DS + d0 + f4 * 4];
        float va[4] = {v.x, v.y, v.z, v.w};
        unsigned short wv[4];
#pragma unroll
        for (int j = 0; j < 4; j++) {
            unsigned short hi = f2bf(va[j]);
            wv[j] = lo_flag ? f2bf(va[j] - bf2f(hi)) : hi;
        }
        int u = f4 >> 1;
        int off = row * 64 + ((u ^ ((row >> 1) & 3)) << 4) + (f4 & 1) * 8;
        uint2 pk;
        pk.x = ((unsigned)wv[1] << 16) | wv[0];
        pk.y = ((unsigned)wv[3] << 16) | wv[2];
        *(uint2*)&ldsT[off] = pk;
    }
    __syncthreads();
    char* g = Bp + ((size_t)nt * 32 + c) * 16384;
#pragma unroll
    for (int i = 0; i < 4; i++) {
        int off = (tid + i * 256) * 16;
        *(uint4*)&g[off] = *(const uint4*)&ldsT[off];
    }
}

// ---------------- MFMA distance-argmin: 256x256 tile, 16 waves x 64x64, 4-slot ring ----------------
// 1024 threads = 16 waves (4M x 4N), wave tile 64x64: acc 4x4 f32x4 = 64 VGPR ->
// target 4 waves/SIMD (16 waves/CU). Sync = round-7 proven scheme: per chunk
// {read frags (compiler-managed lgkm), stage chunk s+3 (2 gloads), 16 MFMA,
// counted vmcnt, barrier}. Ring slot s = chunk mod 4 (32 KB each: A 16K + B 16K).
// vmcnt: steady outstanding after stage = {s+1,s+2,s+3}x2 = 6; VMW4 drains s+1.
#define MM(A, B, C) __builtin_amdgcn_mfma_f32_16x16x32_bf16((A), (B), (C), 0, 0, 0)

#define GLDS(SRC, DOFF)                                                              \
    __builtin_amdgcn_global_load_lds(                                                \
        (const __attribute__((address_space(1))) void*)(SRC),                        \
        (__attribute__((address_space(3))) void*)&lds[DOFF], 16, 0, 0)

#define BAR __builtin_amdgcn_s_barrier()
#define VMW4 asm volatile("s_waitcnt vmcnt(4)" ::: "memory")
#define VMW2 asm volatile("s_waitcnt vmcnt(2)" ::: "memory")
#define VMW0 asm volatile("s_waitcnt vmcnt(0)" ::: "memory")
#define VMNONE (void)0

// stage 32-K chunk C into ring slot (C&3): A 16KB + B 16KB, 1 gload each (1024 thr x 16B)
#define STAGE(C) do {                                                                \
    int c_ = (C);                                                                    \
    int at_ = (c_ < 32) ? (c_ & 15) : (c_ - 16);                                     \
    int bt_ = (c_ < 32) ? c_ : (c_ - 32);                                            \
    int sb_ = (c_ & 3) * 32768;                                                      \
    GLDS(Ap_mt + at_ * 16384 + t16, sb_ + t16);                                      \
    GLDS(Bp_nt + bt_ * 16384 + t16, sb_ + 16384 + t16);                              \
} while (0)

// one chunk: read frags of slot S (B then A), stage, MFMA 4x4, vmcnt, barrier
#define CHUNK(S, DO_STG, STG_C, VMEND, DO_BAR) do {                                  \
    int sb_ = ((S) & 3) * 32768;                                                     \
    bf16x8 bfv[4], af[4];                                                            \
    _Pragma("unroll")                                                                \
    for (int n_ = 0; n_ < 4; n_++)                                                   \
        bfv[n_] = *(const bf16x8*)&lds[sb_ + offB[n_]];                              \
    _Pragma("unroll")                                                                \
    for (int m_ = 0; m_ < 4; m_++)                                                   \
        af[m_] = *(const bf16x8*)&lds[sb_ + offA[m_]];                               \
    if (DO_STG) STAGE(STG_C);                                                        \
    __builtin_amdgcn_s_setprio(1);                                                   \
    _Pragma("unroll")                                                                \
    for (int m_ = 0; m_ < 4; m_++)                                                   \
        _Pragma("unroll")                                                            \
        for (int n_ = 0; n_ < 4; n_++)                                               \
            acc[m_][n_] = MM(af[m_], bfv[n_], acc[m_][n_]);                          \
    __builtin_amdgcn_s_setprio(0);                                                   \
    VMEND;                                                                           \
    if (DO_BAR) BAR;                                                                 \
} while (0)

__global__ __launch_bounds__(1024, 4) void k_mfma(const char* __restrict__ Ap,
                                                  const char* __restrict__ Bp,
                                                  const float* __restrict__ e2,
                                                  float* __restrict__ pb,
                                                  int* __restrict__ pi,
                                                  float* __restrict__ ps) {
    extern __shared__ char lds[];
    // XCD-bijective swizzle: 4096 blocks, 8 XCDs -> 512 consecutive lin per XCD
    int bid = blockIdx.x;
    int lin = (bid >> 3) + (bid & 7) * 512;
    int nt = lin & 15;
    int mt = lin >> 4;

    int tid = threadIdx.x;
    int lane = tid & 63;
    int w = tid >> 6;            // 0..15
    int wr = w >> 2, wc = w & 3; // 4M x 4N waves, each 64x64
    int l15 = lane & 15, lhi = lane >> 4;
    int t16 = tid * 16;          // 1024 threads x 16B = 16 KB

    const char* Ap_mt = Ap + (size_t)mt * 32 * 16384;
    const char* Bp_nt = Bp + (size_t)nt * 32 * 16384;

    // fragment byte offsets within a 16KB chunk: row r, granule u=lhi,
    // off = r*64 + ((u ^ ((r>>1)&3))<<4); (r>>1)&3 == (l15>>1)&3 (base mult of 16)
    int offA[4], offB[4];
#pragma unroll
    for (int m = 0; m < 4; m++) {
        int r = wr * 64 + m * 16 + l15;
        offA[m] = r * 64 + ((lhi ^ ((r >> 1) & 3)) << 4);
    }
#pragma unroll
    for (int n = 0; n < 4; n++) {
        int r = wc * 64 + n * 16 + l15;
        offB[n] = 16384 + r * 64 + ((lhi ^ ((r >> 1) & 3)) << 4);
    }

    f32x4 acc[4][4];
#pragma unroll
    for (int m = 0; m < 4; m++)
#pragma unroll
        for (int n = 0; n < 4; n++) acc[m][n] = (f32x4){0.f, 0.f, 0.f, 0.f};

    // prologue: stage chunks 0,1,2 (6 gloads); drain chunk 0; barrier
    STAGE(0); STAGE(1); STAGE(2);
    VMW4;                        // 6 outstanding -> wait to 4: chunk 0's pair landed
    BAR;

#pragma unroll 1
    for (int s = 0; s < 45; s++) {
        CHUNK(s, 1, s + 3, VMW4, 1);   // stage s+3; end: outstanding {s+2,s+3} -> s+1 landed
    }
    CHUNK(45, 0, 0, VMW2, 1);          // outstanding {47} -> 46 landed
    CHUNK(46, 0, 0, VMW0, 1);          // 47 landed
    CHUNK(47, 0, 0, VMNONE, 0);

    // ---------------- epilogue: per-row argmin ----------------
    __syncthreads();
    float* rb = (float*)lds;
    float* rs = (float*)(lds + 4096);
    int*   ri = (int*)(lds + 8192);

    float e2v[4];
#pragma unroll
    for (int n = 0; n < 4; n++)
        e2v[n] = e2[nt * 256 + wc * 64 + n * 16 + l15];

#pragma unroll
    for (int m = 0; m < 4; m++) {
#pragma unroll
        for (int r2 = 0; r2 < 4; r2++) {
            float bst = 3.4e38f, sec = 3.4e38f;
            int bi = 1 << 30;
#pragma unroll
            for (int n = 0; n < 4; n++) {
                float v = e2v[n] - 2.f * acc[m][n][r2];
                int vi = wc * 64 + n * 16 + l15;
                if (v < bst || (v == bst && vi < bi)) { sec = bst; bst = v; bi = vi; }
                else sec = fminf(sec, v);
            }
#pragma unroll
            for (int mask = 1; mask <= 8; mask <<= 1) {
                float ob = __shfl_xor(bst, mask);
                int obi = __shfl_xor(bi, mask);
                float os = __shfl_xor(sec, mask);
                if (ob < bst || (ob == bst && obi < bi)) {
                    sec = fminf(bst, os); bst = ob; bi = obi;
                } else {
                    sec = fminf(sec, ob);
                }
            }
            if (l15 == 0) {
                int rl = wr * 64 + m * 16 + lhi * 4 + r2;
                int slot = wc * 256 + rl;
                rb[slot] = bst; rs[slot] = sec; ri[slot] = nt * 256 + bi;
            }
        }
    }
    __syncthreads();
    if (tid < 256) {
        float bsv = rb[tid], ssv = rs[tid];
        int biv = ri[tid];
#pragma unroll
        for (int c = 1; c < 4; c++) {
            float ob = rb[c * 256 + tid];
            float os = rs[c * 256 + tid];
            int oi = ri[c * 256 + tid];
            if (ob < bsv || (ob == bsv && oi < biv)) { ssv = fminf(bsv, os); bsv = ob; biv = oi; }
            else ssv = fminf(ssv, ob);
        }
        size_t gr = (size_t)mt * 256 + tid;
        pb[(size_t)nt * NROWS + gr] = bsv;
        pi[(size_t)nt * NROWS + gr] = biv;
        ps[(size_t)nt * NROWS + gr] = ssv;
    }
}

// ---------------- reduce partials -> codes + flagged rows ----------------
__global__ __launch_bounds__(256) void k_reduce(const float* __restrict__ pb,
                                                const int* __restrict__ pi,
                                                const float* __restrict__ ps,
                                                int* __restrict__ codes,
                                                int* __restrict__ list,
                                                int* __restrict__ counter) {
    int row = blockIdx.x * 256 + threadIdx.x;
    float b = 3.4e38f, s = 3.4e38f;
    int bi = 1 << 30;
    for (int nt = 0; nt < NT; nt++) {
        float b2 = pb[(size_t)nt * NROWS + row];
        int i2 = pi[(size_t)nt * NROWS + row];
        float s2 = ps[(size_t)nt * NROWS + row];
        if (b2 < b || (b2 == b && i2 < bi)) { s = fminf(b, s2); b = b2; bi = i2; }
        else s = fminf(s, b2);
    }
    codes[row] = bi;
    if (s - b < REFINE_THR) {
        int p = atomicAdd(counter, 1);
        list[p] = row;
    }
}

// ---------------- fp64 full-scan refine of flagged rows ----------------
__global__ __launch_bounds__(256) void k_refine(const float* __restrict__ x,
                                                const float* __restrict__ emb,
                                                int* __restrict__ codes,
                                                const int* __restrict__ list,
                                                const int* __restrict__ counter) {
    __shared__ float xrow[DS];
    __shared__ double redv[256];
    __shared__ int redi[256];
    int tid = threadIdx.x;
    int nflag = *counter;
    for (int it = blockIdx.x; it < nflag; it += gridDim.x) {
        int row = list[it];
        int b = row >> 12;
        int t = row & 4095;
        for (int d = tid; d < DS; d += 256)
            xrow[d] = x[((size_t)b * DTOT + d) * TT_DIM + t];
        __syncthreads();
        double bv = 1e300;
        int bi = 1 << 30;
        for (int c = tid; c < NCODES; c += 256) {
            const float* er = emb + (size_t)c * DS;
            double s = 0.0;
            for (int d = 0; d < DS; d += 4) {
                float4 ev = *(const float4*)&er[d];
                float4 xv = *(const float4*)&xrow[d];
                double d0 = (double)xv.x - (double)ev.x;
                double d1 = (double)xv.y - (double)ev.y;
                double d2 = (double)xv.z - (double)ev.z;
                double d3 = (double)xv.w - (double)ev.w;
                s += d0 * d0 + d1 * d1 + d2 * d2 + d3 * d3;
            }
            if (s < bv || (s == bv && c < bi)) { bv = s; bi = c; }
        }
        redv[tid] = bv; redi[tid] = bi;
        __syncthreads();
        for (int off = 128; off; off >>= 1) {
            if (tid < off) {
                if (redv[tid + off] < redv[tid] ||
                    (redv[tid + off] == redv[tid] && redi[tid + off] < redi[tid])) {
                    redv[tid] = redv[tid + off];
                    redi[tid] = redi[tid + off];
                }
            }
            __syncthreads();
        }
        if (tid == 0) codes[row] = redi[0];
        __syncthreads();
    }
}

// ---------------- sem output (gather or copy) + sem codes ----------------
__global__ __launch_bounds__(256) void k_sem(const float* __restrict__ x,
                                             const float* __restrict__ emb,
                                             const int* __restrict__ codes,
                                             const float* __restrict__ sem_probs,
                                             float* __restrict__ out) {
    __shared__ float q[TT * (DS + 1)];
    __shared__ int rowc[TT];
    int b = blockIdx.y, t0 = blockIdx.x * TT;
    bool mask = sem_probs[b] < 0.5f;
    float* outb = out + (size_t)b * DTOT * TT_DIM + t0;
    const float* xb = x + (size_t)b * DTOT * TT_DIM + t0;
    const size_t QOFF = (size_t)BB * DTOT * TT_DIM;

    if (threadIdx.x < TT) {
        int code = codes[b * TT_DIM + t0 + threadIdx.x];
        rowc[threadIdx.x] = code;
        out[QOFF + ((size_t)b * 33) * TT_DIM + t0 + threadIdx.x] = (float)code;
    }
    __syncthreads();

    if (mask) {
        for (int i = 0; i < TT * DS / 256; i++) {
            int idx = threadIdx.x + i * 256;
            int tt = idx >> 9, d = idx & 511;
            q[tt * (DS + 1) + d] = emb[(size_t)rowc[tt] * DS + d];
        }
        __syncthreads();
        for (int i = 0; i < TT * DS / 256; i++) {
            int idx = threadIdx.x + i * 256;
            int d = idx >> 5, tt = idx & 31;
            outb[(size_t)d * TT_DIM + tt] = q[tt * (DS + 1) + d];
        }
    } else {
        for (int i = 0; i < TT * DS / 256; i++) {
            int idx = threadIdx.x + i * 256;
            int d = idx >> 5, tt = idx & 31;
            outb[(size_t)d * TT_DIM + tt] = xb[(size_t)d * TT_DIM + tt];
        }
    }
}

// ---------------- aco elementwise ----------------
__global__ __launch_bounds__(256) void k_aco(const float* __restrict__ x,
                                             const float* __restrict__ noise,
                                             const float* __restrict__ aco_probs,
                                             float* __restrict__ out) {
    int idx = blockIdx.x * 256 + threadIdx.x;
    int t4 = idx & 1023;
    int bc = idx >> 10;
    int ch = bc & 31;
    int b = bc >> 5;
    const float4 xv = *(const float4*)&x[((size_t)(b * DTOT + DS + ch)) * TT_DIM + t4 * 4];
    const float4 nv = *(const float4*)&noise[((size_t)(b * 32 + ch)) * TT_DIM + t4 * 4];
    float p = aco_probs[b];
    const size_t QOFF = (size_t)BB * DTOT * TT_DIM;

    float zq[4], cq[4];
    float xa[4] = {xv.x, xv.y, xv.z, xv.w};
    float na[4] = {nv.x, nv.y, nv.z, nv.w};
#pragma unroll
    for (int i = 0; i < 4; i++) {
        float zb = tanhf(xa[i]) * HALFV;
        float z;
        if (p < 0.5f) z = rintf(zb);
        else if (p < 0.75f) z = fminf(fmaxf(zb + na[i], -HALFV), HALFV);
        else z = zb;
        zq[i] = z / HALFV;
        cq[i] = fminf(fmaxf(rintf(z + HALFV), 0.f), 15.f);
    }
    float4 qo = {zq[0], zq[1], zq[2], zq[3]};
    float4 co = {cq[0], cq[1], cq[2], cq[3]};
    *(float4*)&out[((size_t)(b * DTOT + DS + ch)) * TT_DIM + t4 * 4] = qo;
    *(float4*)&out[QOFF + ((size_t)(b * 33 + 1 + ch)) * TT_DIM + t4 * 4] = co;
}

extern "C" void kernel_launch(void* const* d_in, const int* in_sizes, int n_in,
                              void* d_out, int out_size, void* d_ws, size_t ws_size,
                              hipStream_t stream) {
    const float* x         = (const float*)d_in[0];
    const float* esum      = (const float*)d_in[1];
    const float* usage     = (const float*)d_in[2];
    const float* sem_probs = (const float*)d_in[3];
    const float* aco_probs = (const float*)d_in[4];
    const float* noise     = (const float*)d_in[5];
    float* out = (float*)d_out;

    char* w = (char*)d_ws;
    float* emb    = (float*)w;                         // 8,388,608
    float* e2     = (float*)(w + 8388608);             // 16,384
    char*  Ap     = w + 8404992;                       // 134,217,728
    char*  Bp     = w + 142622720;                     // 8,388,608
    float* pb     = (float*)(w + 151011328);           // 4,194,304
    int*   pi     = (int*)(w + 155205632);             // 4,194,304
    float* ps     = (float*)(w + 159399936);           // 4,194,304
    int*   codes  = (int*)(w + 163594240);             // 262,144
    int*   list   = (int*)(w + 163856384);             // 262,144
    int*   counter= (int*)(w + 164118528);             // 4

    k_emb<<<NCODES, 256, 0, stream>>>(esum, usage, emb, e2, counter);
    k_packA<<<dim3(MT, 16), 256, 0, stream>>>(x, Ap);
    k_packB<<<dim3(NT, 32), 256, 0, stream>>>(emb, Bp);
    k_mfma<<<NT * MT, 1024, 131072, stream>>>(Ap, Bp, e2, pb, pi, ps);
    k_reduce<<<NROWS / 256, 256, 0, stream>>>(pb, pi, ps, codes, list, counter);
    k_refine<<<256, 256, 0, stream>>>(x, emb, codes, list, counter);
    k_sem<<<dim3(TT_DIM / TT, BB), 256, 0, stream>>>(x, emb, codes, sem_probs, out);
    k_aco<<<(BB * 32 * TT_DIM) / (256 * 4), 256, 0, stream>>>(x, noise, aco_probs, out);
}